// Round 3
// baseline (74.171 us; speedup 1.0000x reference)
//
#include <hip/hip_runtime.h>

namespace {
constexpr int kB = 16384;
constexpr int kC = 1000;
constexpr int kNElem = kB * kC;          // 16,384,000
constexpr int kNV8 = kNElem / 8;         // 2,048,000
constexpr int kV8PerRow = kC / 8;        // 125
constexpr int kBlocks = 2048;            // 8 wg/CU resident
constexpr int kThreads = 256;
}

// ws layout (19 x 4B):
//   wsf[0..8]  : float cum_j  = sum of bce over elements with s >= t_j   (j=1..9)
//   wsf[9]     : float T      = sum of bce over all elements
//   wsu[10..18]: uint  cnt_j  = count of elements with s >= t_j          (j=1..9)

__global__ __launch_bounds__(kThreads) void ghmc_main(
    const float* __restrict__ logits,
    const int* __restrict__ tgt,
    float* __restrict__ wsf)
{
    // t_j = logit(j/10) = ln(j/(10-j)), j = 1..9
    constexpr float th[9] = {
        -2.19722458f, -1.38629436f, -0.84729786f, -0.40546511f, 0.0f,
         0.40546511f,  0.84729786f,  1.38629436f,  2.19722458f};

    float    cum[9] = {0.f,0.f,0.f,0.f,0.f,0.f,0.f,0.f,0.f};
    unsigned cnt[9] = {0u,0u,0u,0u,0u,0u,0u,0u,0u};
    float T = 0.f;

    const int stride = gridDim.x * blockDim.x;
    for (int i = blockIdx.x * blockDim.x + threadIdx.x; i < kNV8; i += stride) {
        const int row = i / kV8PerRow;                       // magic-mul division
        const int dt  = tgt[row] - (i - row * kV8PerRow) * 8; // only used by rare branch
        float lv[8];
        *reinterpret_cast<float4*>(&lv[0]) = reinterpret_cast<const float4*>(logits)[2 * i];
        *reinterpret_cast<float4*>(&lv[4]) = reinterpret_cast<const float4*>(logits)[2 * i + 1];

        // main path: assume every element is non-target (s = L). Pure function
        // of the float4 data -> no dependence on the tgt load.
        #pragma unroll
        for (int e = 0; e < 8; ++e) {
            const float L   = lv[e];
            const float en  = __expf(-fabsf(L));
            const float lg  = __logf(1.f + en);     // log1p(exp(-|L|))
            const float bce = fmaxf(L, 0.f) + lg;   // softplus(L)
            T += bce;
            #pragma unroll
            for (int j = 0; j < 9; ++j) {
                const bool m = (L >= th[j]);        // one v_cmp
                cum[j] += m ? bce : 0.f;            // cndmask + add
                cnt[j] += (unsigned)m;              // addc
            }
        }

        // rare correction: the row's target element is in this 8-chunk.
        // ~26% of wave-iterations have >=1 active lane, 1-2 lanes each.
        if (__builtin_expect((unsigned)dt < 8u, 0)) {
            // select lv[dt] without runtime array indexing (avoid scratch)
            float L = lv[0];
            #pragma unroll
            for (int e = 1; e < 8; ++e) L = (dt == e) ? lv[e] : L;
            const float en = __expf(-fabsf(L));
            const float lg = __logf(1.f + en);
            const float bn = fmaxf(L, 0.f) + lg;    // what the main path added
            const float bt = fmaxf(-L, 0.f) + lg;   // what a target element needs
            T += bt - bn;
            #pragma unroll
            for (int j = 0; j < 9; ++j) {
                const bool mt = (-L >= th[j]);
                const bool mn = ( L >= th[j]);
                cum[j] += (mt ? bt : 0.f) - (mn ? bn : 0.f);
                cnt[j] += (unsigned)mt - (unsigned)mn;  // unsigned wrap ok
            }
        }
    }

    // 64-lane wave butterfly reduction (19 values)
    #pragma unroll
    for (int off = 32; off > 0; off >>= 1) {
        T += __shfl_down(T, off);
        #pragma unroll
        for (int j = 0; j < 9; ++j) {
            cum[j] += __shfl_down(cum[j], off);
            cnt[j] += __shfl_down(cnt[j], off);
        }
    }

    __shared__ float    s_f[kThreads / 64][10];
    __shared__ unsigned s_u[kThreads / 64][9];
    const int wave = threadIdx.x >> 6;
    const int lane = threadIdx.x & 63;
    if (lane == 0) {
        #pragma unroll
        for (int j = 0; j < 9; ++j) { s_f[wave][j] = cum[j]; s_u[wave][j] = cnt[j]; }
        s_f[wave][9] = T;
    }
    __syncthreads();
    if (threadIdx.x < 10) {
        const int j = threadIdx.x;
        const float v = s_f[0][j] + s_f[1][j] + s_f[2][j] + s_f[3][j];
        atomicAdd(&wsf[j], v);
    } else if (threadIdx.x < 19) {
        const int j = threadIdx.x - 10;
        const unsigned v = s_u[0][j] + s_u[1][j] + s_u[2][j] + s_u[3][j];
        atomicAdd(reinterpret_cast<unsigned*>(wsf) + 10 + j, v);
    }
}

__global__ void ghmc_final(const float* __restrict__ wsf, float* __restrict__ out)
{
    if (threadIdx.x == 0 && blockIdx.x == 0) {
        const unsigned* wsu = reinterpret_cast<const unsigned*>(wsf);
        float cumk[11], cntk[11];
        cumk[0] = wsf[9];                 // T: all elements
        cntk[0] = (float)kNElem;
        #pragma unroll
        for (int j = 1; j <= 9; ++j) {
            cumk[j] = wsf[j - 1];
            cntk[j] = (float)wsu[9 + j];
        }
        cumk[10] = 0.f; cntk[10] = 0.f;
        float acc = 0.f, n = 0.f;
        #pragma unroll
        for (int k = 0; k < 10; ++k) {
            const float Nk = cntk[k] - cntk[k + 1];
            if (Nk > 0.f) {
                n += 1.f;
                acc += (cumk[k] - cumk[k + 1]) / Nk;
            }
        }
        out[0] = acc / fmaxf(n, 1.f);     // LOSS_WEIGHT = 1
    }
}

extern "C" void kernel_launch(void* const* d_in, const int* in_sizes, int n_in,
                              void* d_out, int out_size, void* d_ws, size_t ws_size,
                              hipStream_t stream)
{
    const float* logits = (const float*)d_in[0];
    const int*   tgt    = (const int*)d_in[1];
    float* wsf = (float*)d_ws;
    hipMemsetAsync(d_ws, 0, 19 * sizeof(float), stream);
    ghmc_main<<<kBlocks, kThreads, 0, stream>>>(logits, tgt, wsf);
    ghmc_final<<<1, 64, 0, stream>>>(wsf, (float*)d_out);
}